// Round 15
// baseline (347.997 us; speedup 1.0000x reference)
//
#include <hip/hip_runtime.h>

using u16 = unsigned short;
using u32 = unsigned int;

typedef float f32x4 __attribute__((ext_vector_type(4)));
typedef __bf16 bf16x8 __attribute__((ext_vector_type(8)));

// ---------- helpers ----------
__device__ __forceinline__ u16 f2bf(float f){
  u32 u = __builtin_bit_cast(u32, f);
  u32 r = (u + 0x7fffu + ((u >> 16) & 1u)) >> 16;   // RNE
  return (u16)r;
}
__device__ __forceinline__ float bf2f(u16 h){
  u32 u = ((u32)h) << 16;
  return __builtin_bit_cast(float, u);
}
__device__ __forceinline__ void gl2lds16(const void* g, void* l){
  __builtin_amdgcn_global_load_lds((const __attribute__((address_space(1))) u32*)g,
                                   (__attribute__((address_space(3))) u32*)l, 16, 0, 0);
}
__device__ __forceinline__ int swz24(int ck, int r){ return (ck & 24) | ((ck ^ r) & 7); }
__device__ __forceinline__ u32 cvtpk_bf16(float a, float b){
  u32 r; asm("v_cvt_pk_bf16_f32 %0, %1, %2" : "=v"(r) : "v"(a), "v"(b)); return r;
}
__device__ __forceinline__ float exp2_raw(float x){
  float r; asm("v_exp_f32 %0, %1" : "=v"(r) : "v"(x)); return r;   // 2^x
}

// ---------- prep: 5 weight transposes + rope tables + x cvt, one launch ----------
// id ranges: [0,3072) q_a | [3072,5120) kv_a | [5120,9728) q_b | [9728,10752) kv_b
//            [10752,14848) o_w | [14848,15104) rope | [15104,23296) cvt
__global__ __launch_bounds__(256) void prep_kernel(const float* __restrict__ hs, u16* __restrict__ XB,
                                                   const float* __restrict__ q_a_w,  u16* __restrict__ Wqa,
                                                   const float* __restrict__ kv_a_w, u16* __restrict__ Wkva,
                                                   const float* __restrict__ q_b_w,  u16* __restrict__ Wqb,
                                                   const float* __restrict__ kv_b_w, u16* __restrict__ Wkvb,
                                                   const float* __restrict__ o_w,    u16* __restrict__ Wo,
                                                   float* __restrict__ cosT, float* __restrict__ sinT){
  __shared__ float tile[32][33];
  const int id = blockIdx.x;
  if (id >= 15104){                    // cvt x -> bf16
    long i = ((long)(id - 15104)*256 + threadIdx.x)*4;
    float4 v = *(const float4*)(hs + i);
    u16 o[4] = { f2bf(v.x), f2bf(v.y), f2bf(v.z), f2bf(v.w) };
    *(ushort4*)(XB + i) = *(ushort4*)o;
    return;
  }
  if (id >= 14848){                    // rope tables (f64 trig)
    int idx = (id - 14848)*256 + threadIdx.x;
    int t = idx >> 5, d = idx & 31;
    double inv = pow(10000.0, -(double)d / 32.0);
    double a = (double)t * inv;
    cosT[idx] = (float)cos(a);
    sinT[idx] = (float)sin(a);
    return;
  }
  const float* in; u16* out; int K, N, lid;
  if      (id <  3072){ in = q_a_w;  out = Wqa;  K = 2048; N = 1536; lid = id; }
  else if (id <  5120){ in = kv_a_w; out = Wkva; K = 2048; N = 1024; lid = id - 3072; }
  else if (id <  9728){ in = q_b_w;  out = Wqb;  K = 1536; N = 3072; lid = id - 5120; }
  else if (id < 10752){ in = kv_b_w; out = Wkvb; K =  512; N = 2048; lid = id - 9728; }
  else                { in = o_w;    out = Wo;   K = 2048; N = 2048; lid = id - 10752; }
  const int tx = threadIdx.x & 31, ty = threadIdx.x >> 5;
  const int nb = N >> 5;
  const int n0 = (lid % nb)*32, k0 = (lid / nb)*32;
  for (int i = ty; i < 32; i += 8)
    tile[i][tx] = in[(size_t)(k0+i)*N + n0+tx];
  __syncthreads();
  for (int i = ty; i < 32; i += 8)
    out[(size_t)(n0+i)*K + k0+tx] = f2bf(tile[tx][i]);
}

// ---------- block remap: XCD-grouped, 4 M-panels share each B-panel per XCD ----------
__device__ __forceinline__ void remap_id(int id, int& bx, int& by){
  bx = id >> 5;
  by = ((id & 7) << 2) | ((id >> 3) & 3);
}

// ---------- m97-style 128x128 bf16 MFMA GEMM (single-buffer, proven) ----------
template<int OUT_BF16>
__global__ __launch_bounds__(256) void gemm_bt(const u16* __restrict__ A,
                                               const u16* __restrict__ Bt,
                                               void* __restrict__ Cout,
                                               int M, int N, int K, float cscale){
  __shared__ u16 As[128*32];
  __shared__ u16 Bs[128*32];
  const int tid = threadIdx.x, lane = tid & 63, wave = tid >> 6;
  int bx, by; remap_id(blockIdx.y*gridDim.x + blockIdx.x, bx, by);
  const int m0 = by*128, n0 = bx*128;
  const int wm = (wave >> 1)*64, wn = (wave & 1)*64;
  const int g = lane >> 4, lr = lane & 15;
  f32x4 acc[4][4] = {};
  const int sr = (wave*2)*16 + (lane >> 2);
  const int sc = (lane & 3)*8;
  for (int k0 = 0; k0 < K; k0 += 32){
    __syncthreads();
    #pragma unroll
    for (int i = 0; i < 2; i++){
      int c = wave*2 + i;
      int r = sr + i*16;
      gl2lds16(A  + (size_t)(m0+r)*K + k0 + sc, (char*)As + c*1024);
      gl2lds16(Bt + (size_t)(n0+r)*K + k0 + sc, (char*)Bs + c*1024);
    }
    __syncthreads();
    bf16x8 af[4], bfr[4];
    #pragma unroll
    for (int mi = 0; mi < 4; mi++) af[mi]  = *reinterpret_cast<const bf16x8*>(&As[(wm+mi*16+lr)*32 + g*8]);
    #pragma unroll
    for (int ni = 0; ni < 4; ni++) bfr[ni] = *reinterpret_cast<const bf16x8*>(&Bs[(wn+ni*16+lr)*32 + g*8]);
    #pragma unroll
    for (int mi = 0; mi < 4; mi++)
      #pragma unroll
      for (int ni = 0; ni < 4; ni++)
        acc[mi][ni] = __builtin_amdgcn_mfma_f32_16x16x32_bf16(af[mi], bfr[ni], acc[mi][ni], 0,0,0);
  }
  #pragma unroll
  for (int mi = 0; mi < 4; mi++)
    #pragma unroll
    for (int ni = 0; ni < 4; ni++)
      #pragma unroll
      for (int r = 0; r < 4; r++){
        int row = m0 + wm + mi*16 + g*4 + r;
        int col = n0 + wn + ni*16 + lr;
        float v = acc[mi][ni][r];
        if (OUT_BF16) ((u16*)Cout)[(size_t)row*N + col] = f2bf(v*cscale);
        else          ((float*)Cout)[(size_t)row*N + col] = v;
      }
}

// ---------- merged q_b (+RoPE, qscale*log2e) and kv_b GEMM in one launch ----------
// blocks [0,768): qb N=3072 K=1536 ; [768,1280): kvb N=2048 K=512
__global__ __launch_bounds__(256) void gemm_qb_kvb(const u16* __restrict__ Qlat,
                                                   const u16* __restrict__ Wqb,
                                                   u16* __restrict__ QB,
                                                   const float* __restrict__ cosT,
                                                   const float* __restrict__ sinT,
                                                   const u16* __restrict__ KVlat,
                                                   const u16* __restrict__ Wkvb,
                                                   u16* __restrict__ KVB){
  constexpr float qscale = 0.07216878364870322f * 1.44269504088896340f;  // 192^-0.5 * log2(e)
  __shared__ u16 As[128*32];
  __shared__ u16 Bs[128*32];
  const int id = blockIdx.x;
  const u16 *A, *Bt; u16* C; int N, K; bool isqb;
  int bx, by;
  if (id < 768){ A = Qlat;  Bt = Wqb;  C = QB;  N = 3072; K = 1536; isqb = true;  remap_id(id, bx, by); }
  else         { A = KVlat; Bt = Wkvb; C = KVB; N = 2048; K =  512; isqb = false; remap_id(id - 768, bx, by); }
  const int tid = threadIdx.x, lane = tid & 63, wave = tid >> 6;
  const int m0 = by*128, n0 = bx*128;
  const int wm = (wave >> 1)*64, wn = (wave & 1)*64;
  const int g = lane >> 4, lr = lane & 15;
  f32x4 acc[4][4] = {};
  const int sr = (wave*2)*16 + (lane >> 2);
  const int sc = (lane & 3)*8;
  for (int k0 = 0; k0 < K; k0 += 32){
    __syncthreads();
    #pragma unroll
    for (int i = 0; i < 2; i++){
      int c = wave*2 + i;
      int r = sr + i*16;
      gl2lds16(A  + (size_t)(m0+r)*K + k0 + sc, (char*)As + c*1024);
      gl2lds16(Bt + (size_t)(n0+r)*K + k0 + sc, (char*)Bs + c*1024);
    }
    __syncthreads();
    bf16x8 af[4], bfr[4];
    #pragma unroll
    for (int mi = 0; mi < 4; mi++) af[mi]  = *reinterpret_cast<const bf16x8*>(&As[(wm+mi*16+lr)*32 + g*8]);
    #pragma unroll
    for (int ni = 0; ni < 4; ni++) bfr[ni] = *reinterpret_cast<const bf16x8*>(&Bs[(wn+ni*16+lr)*32 + g*8]);
    #pragma unroll
    for (int mi = 0; mi < 4; mi++)
      #pragma unroll
      for (int ni = 0; ni < 4; ni++)
        acc[mi][ni] = __builtin_amdgcn_mfma_f32_16x16x32_bf16(af[mi], bfr[ni], acc[mi][ni], 0,0,0);
  }
  if (isqb){
    const bool rope = (((n0 + wn) >> 6) % 3) == 2;
    #pragma unroll
    for (int mi = 0; mi < 4; mi++)
      #pragma unroll
      for (int r = 0; r < 4; r++){
        int row = m0 + wm + mi*16 + g*4 + r;
        int t = row & 2047;
        u16* crow = C + (size_t)row*3072 + n0 + wn;
        if (rope){
          #pragma unroll
          for (int np = 0; np < 2; np++){
            int dp = np*16 + lr;
            float x1 = acc[mi][np][r]*qscale, x2 = acc[mi][np+2][r]*qscale;
            float cv = cosT[t*32 + dp], sv = sinT[t*32 + dp];
            crow[dp]      = f2bf(x1*cv - x2*sv);
            crow[dp + 32] = f2bf(x2*cv + x1*sv);
          }
        } else {
          #pragma unroll
          for (int ni = 0; ni < 4; ni++)
            crow[ni*16 + lr] = f2bf(acc[mi][ni][r]*qscale);
        }
      }
  } else {
    #pragma unroll
    for (int mi = 0; mi < 4; mi++)
      #pragma unroll
      for (int ni = 0; ni < 4; ni++)
        #pragma unroll
        for (int r = 0; r < 4; r++){
          int row = m0 + wm + mi*16 + g*4 + r;
          int col = n0 + wn + ni*16 + lr;
          C[(size_t)row*2048 + col] = f2bf(acc[mi][ni][r]);
        }
  }
}

// ---------- merged rmsnorm(q) + rmsnorm(kv)+rope(k) over R23 rows ----------
__global__ __launch_bounds__(256) void norm_split(const u16* __restrict__ R23,
                                                  const float* __restrict__ q_ln,
                                                  const float* __restrict__ kv_ln,
                                                  const float* __restrict__ cosT,
                                                  const float* __restrict__ sinT,
                                                  u16* __restrict__ Qlat,
                                                  u16* __restrict__ KVlat,
                                                  u16* __restrict__ Kf){
  int row = blockIdx.x;                       // 0..4095
  int t = row & 2047, b = row >> 11;
  const u16* x = R23 + (size_t)row*2560;
  int c = threadIdx.x;
  float xq[8]; float ssq = 0.f;
  if (c < 192){
    ushort4 a = *(const ushort4*)(x + c*8);
    ushort4 bq = *(const ushort4*)(x + c*8 + 4);
    u16 e[8] = {a.x,a.y,a.z,a.w,bq.x,bq.y,bq.z,bq.w};
    #pragma unroll
    for (int j = 0; j < 8; j++){ xq[j] = bf2f(e[j]); ssq += xq[j]*xq[j]; }
  }
  float xk[4]; float ssk = 0.f;
  if (c < 128){
    ushort4 a = *(const ushort4*)(x + 1536 + c*4);
    u16 e[4] = {a.x,a.y,a.z,a.w};
    #pragma unroll
    for (int j = 0; j < 4; j++){ xk[j] = bf2f(e[j]); ssk += xk[j]*xk[j]; }
  }
  #pragma unroll
  for (int m = 1; m < 64; m <<= 1){
    ssq += __shfl_xor(ssq, m, 64);
    ssk += __shfl_xor(ssk, m, 64);
  }
  __shared__ float pq[4], pk[4];
  if ((c & 63) == 0){ pq[c >> 6] = ssq; pk[c >> 6] = ssk; }
  __syncthreads();
  float invq = rsqrtf((pq[0]+pq[1]+pq[2]+pq[3]) / 1536.0f + 1e-6f);
  float invk = rsqrtf((pk[0]+pk[1]+pk[2]+pk[3]) / 512.0f + 1e-6f);
  if (c < 192){
    u16 o[8];
    #pragma unroll
    for (int j = 0; j < 8; j++) o[j] = f2bf(xq[j]*invq*q_ln[c*8+j]);
    *(ushort4*)(Qlat + (size_t)row*1536 + c*8)     = *(ushort4*)o;
    *(ushort4*)(Qlat + (size_t)row*1536 + c*8 + 4) = *(ushort4*)(o+4);
  }
  if (c < 128){
    u16 o[4];
    #pragma unroll
    for (int j = 0; j < 4; j++) o[j] = f2bf(xk[j]*invk*kv_ln[c*4+j]);
    *(ushort4*)(KVlat + (size_t)row*512 + c*4) = *(ushort4*)o;
  }
  // rope on k (cols 2048..2559): 8 heads x 32 pairs
  int kh = c >> 5, dp = c & 31;
  float x1 = bf2f(x[2048 + kh*64 + dp]), x2 = bf2f(x[2048 + kh*64 + dp + 32]);
  float cv = cosT[t*32 + dp], sv = sinT[t*32 + dp];
  float o1 = x1*cv - x2*sv;
  float o2 = x2*cv + x1*sv;
  u16* kr = Kf + ((size_t)(b*8 + kh)*2048 + t)*192;
  int c1 = 128 + dp, c2 = 128 + dp + 32;
  kr[(swz24(c1 >> 3, t) << 3) | (c1 & 7)] = f2bf(o1);
  kr[(swz24(c2 >> 3, t) << 3) | (c2 & 7)] = f2bf(o2);
}

// ---------- kv rearrange: knope copy -> Kf (swizzled) + V transpose -> vT ----------
__global__ __launch_bounds__(256) void kv_rearrange(const u16* __restrict__ kv,
                                                    u16* __restrict__ vT,
                                                    u16* __restrict__ Kf){
  int bid = blockIdx.x;                        // 2*8*32
  int tt = bid & 31, kvh = (bid >> 5) & 7, b = bid >> 8;
  int t0 = tt*64;
  __shared__ u16 tile[64][136];
  int tid = threadIdx.x;
  #pragma unroll
  for (int i = 0; i < 4; i++){
    int c2 = tid + i*256;
    int rr = c2 >> 4, ck = c2 & 15;
    int t = t0 + rr;
    int ck2 = (ck & 8) | ((ck ^ t) & 7);
    uint4 v = *(const uint4*)(kv + ((size_t)(b*2048 + t))*2048 + kvh*256 + ck*8);
    *(uint4*)(Kf + ((size_t)(b*8 + kvh)*2048 + t)*192 + ck2*8) = v;
  }
  #pragma unroll
  for (int i = 0; i < 4; i++){
    int c = tid + i*256;
    int r = c >> 4, ck = c & 15;
    const u16* src = kv + ((size_t)(b*2048 + t0 + r))*2048 + kvh*256 + 128 + ck*8;
    *(uint4*)&tile[r][ck*8] = *(const uint4*)src;
  }
  __syncthreads();
  #pragma unroll
  for (int i = 0; i < 4; i++){
    int c = tid + i*256;
    int vd = c >> 3, tc = c & 7;
    int stc = tc ^ (vd & 7);
    uint4 tv;
    u16* tp = (u16*)&tv;
    #pragma unroll
    for (int j = 0; j < 8; j++) tp[j] = tile[tc*8 + j][vd];
    *(uint4*)(vT + ((size_t)(b*8 + kvh)*128 + vd)*2048 + t0 + stc*8) = tv;
  }
}

// ---------- flash attention: R14 champion (swapped-QK, raw exp2, deferred lq) ----------
__global__ __launch_bounds__(256, 2) void attn_kernel(const u16* __restrict__ Q,
                                                      const u16* __restrict__ Kf,
                                                      const u16* __restrict__ Vt,
                                                      u16* __restrict__ Oa){
  constexpr int T = 2048;
  constexpr int NT = T/64;
  __shared__ u16 Ks[64*192];
  __shared__ u16 Vs[2][128*64];
  __shared__ u16 Ps[4][2048];
  const int tid = threadIdx.x, lane = tid & 63, wave = tid >> 6;
  const int g = lane >> 4, lr = lane & 15;

  const int wg = blockIdx.x;                 // 0..511
  const int role = (wg & 7)*64 + (wg >> 3);
  const int grp = role >> 5;                 // b*8 + kvh
  const int b = grp >> 3, kvh = grp & 7;
  const int within = role & 31;
  const int h = kvh*2 + (within >> 4);
  const int q0 = (within & 15)*128 + wave*32;

  bf16x8 aq[2][6];
  #pragma unroll
  for (int qg = 0; qg < 2; qg++){
    const u16* qrow = Q + ((size_t)b*T + q0 + qg*16 + lr)*3072 + h*192;
    #pragma unroll
    for (int kc = 0; kc < 6; kc++)
      aq[qg][kc] = *reinterpret_cast<const bf16x8*>(qrow + kc*32 + g*8);
  }
  const u16* Kbase = Kf + (size_t)(b*8 + kvh)*T*192;
  const u16* Vbase = Vt + (size_t)(b*8 + kvh)*128*T;

  f32x4 ovb[2][8] = {};
  float mq[2] = {-1e30f, -1e30f};
  float lq[2] = {0.f, 0.f};

  auto stageK = [&](int kt){
    const u16* ksrc = Kbase + (size_t)kt*12288 + wave*3072 + lane*8;
    #pragma unroll
    for (int i = 0; i < 6; i++)
      gl2lds16(ksrc + i*512, (char*)Ks + (wave*6 + i)*1024);
  };
  auto stageV = [&](int kt, int buf){
    #pragma unroll
    for (int i = 0; i < 4; i++){
      int c = wave*4 + i;
      const u16* vsrc = Vbase + (size_t)(c*8 + (lane >> 3))*T + kt*64 + (lane & 7)*8;
      gl2lds16(vsrc, (char*)(&Vs[0][0]) + buf*16384 + c*1024);
    }
  };

  stageK(0);
  stageV(0, 0);
  __syncthreads();

  int buf = 0;
  for (int kt = 0; kt < NT; kt++){
    const bool notlast = (kt + 1 < NT);
    if (notlast) stageV(kt + 1, buf ^ 1);

    f32x4 s[2][4];
    __builtin_amdgcn_s_setprio(1);
    #pragma unroll
    for (int nb = 0; nb < 4; nb++){
      const int row = nb*16 + lr;
      f32x4 a0 = {0.f,0.f,0.f,0.f}, a1 = {0.f,0.f,0.f,0.f};
      #pragma unroll
      for (int kc = 0; kc < 6; kc++){
        int ckl = swz24(kc*4 + g, row);
        bf16x8 kf = *reinterpret_cast<const bf16x8*>(&Ks[row*192 + ckl*8]);
        a0 = __builtin_amdgcn_mfma_f32_16x16x32_bf16(kf, aq[0][kc], a0, 0,0,0);
        a1 = __builtin_amdgcn_mfma_f32_16x16x32_bf16(kf, aq[1][kc], a1, 0,0,0);
      }
      s[0][nb] = a0; s[1][nb] = a1;
    }
    __builtin_amdgcn_s_setprio(0);

    asm volatile("s_waitcnt lgkmcnt(0)" ::: "memory");
    __builtin_amdgcn_s_barrier();
    __builtin_amdgcn_sched_barrier(0);
    if (notlast) stageK(kt + 1);

    #pragma unroll
    for (int qg = 0; qg < 2; qg++){
      float pm = s[qg][0][0];
      #pragma unroll
      for (int nb = 0; nb < 4; nb++)
        #pragma unroll
        for (int r = 0; r < 4; r++)
          if (nb || r) pm = fmaxf(pm, s[qg][nb][r]);
      pm = fmaxf(pm, __shfl_xor(pm, 16, 64));
      pm = fmaxf(pm, __shfl_xor(pm, 32, 64));
      if (!__all(pm <= mq[qg] + 8.f)){
        float mn = fmaxf(mq[qg], pm);
        float corr = exp2_raw(mq[qg] - mn);
        mq[qg] = mn;
        lq[qg] *= corr;
        #pragma unroll
        for (int r = 0; r < 4; r++){
          float cr = __shfl(corr, (lane & 48) | (g*4 + r), 64);
          #pragma unroll
          for (int vb = 0; vb < 8; vb++) ovb[qg][vb][r] *= cr;
        }
      }
      float ls = 0.f;
      #pragma unroll
      for (int nb = 0; nb < 4; nb++){
        float e0 = exp2_raw(s[qg][nb][0] - mq[qg]);
        float e1 = exp2_raw(s[qg][nb][1] - mq[qg]);
        float e2 = exp2_raw(s[qg][nb][2] - mq[qg]);
        float e3 = exp2_raw(s[qg][nb][3] - mq[qg]);
        ls += (e0 + e1) + (e2 + e3);
        int stc = (2*nb + (g >> 1)) ^ (lr & 7);
        volatile u32* p = (volatile u32*)&Ps[wave][qg*1024 + lr*64 + stc*8 + (g & 1)*4];
        p[0] = cvtpk_bf16(e0, e1);
        p[1] = cvtpk_bf16(e2, e3);
      }
      lq[qg] += ls;
    }

    asm volatile("s_waitcnt lgkmcnt(0)" ::: "memory");
    __builtin_amdgcn_sched_barrier(0);

    bf16x8 ap[2][2];
    #pragma unroll
    for (int qg = 0; qg < 2; qg++)
      #pragma unroll
      for (int k2 = 0; k2 < 2; k2++){
        int ck = (k2*4 + g) ^ (lr & 7);
        ap[qg][k2] = *reinterpret_cast<const bf16x8*>(&Ps[wave][qg*1024 + lr*64 + ck*8]);
      }
    __builtin_amdgcn_s_setprio(1);
    #pragma unroll
    for (int vb = 0; vb < 8; vb++)
      #pragma unroll
      for (int k2 = 0; k2 < 2; k2++){
        int vd = vb*16 + lr;
        int ck = (k2*4 + g) ^ (vd & 7);
        bf16x8 bv = *reinterpret_cast<const bf16x8*>(&Vs[buf][vd*64 + ck*8]);
        ovb[0][vb] = __builtin_amdgcn_mfma_f32_16x16x32_bf16(ap[0][k2], bv, ovb[0][vb], 0,0,0);
        ovb[1][vb] = __builtin_amdgcn_mfma_f32_16x16x32_bf16(ap[1][k2], bv, ovb[1][vb], 0,0,0);
      }
    __builtin_amdgcn_s_setprio(0);

    if (notlast) __syncthreads();
    buf ^= 1;
  }

  #pragma unroll
  for (int qg = 0; qg < 2; qg++){
    float lt = lq[qg];
    lt += __shfl_xor(lt, 16, 64);
    lt += __shfl_xor(lt, 32, 64);
    float invq = 1.0f / lt;
    float inv_r[4];
    #pragma unroll
    for (int r = 0; r < 4; r++)
      inv_r[r] = __shfl(invq, (lane & 48) | (g*4 + r), 64);
    u16* obase = Oa + ((size_t)b*T + q0 + qg*16)*2048 + h*128;
    #pragma unroll
    for (int vb = 0; vb < 8; vb++)
      #pragma unroll
      for (int r = 0; r < 4; r++)
        obase[(size_t)(g*4 + r)*2048 + vb*16 + lr] = f2bf(ovb[qg][vb][r]*inv_r[r]);
  }
}

// ---------- launch ----------
extern "C" void kernel_launch(void* const* d_in, const int* in_sizes, int n_in,
                              void* d_out, int out_size, void* d_ws, size_t ws_size,
                              hipStream_t stream){
  const float* hs      = (const float*)d_in[0];
  const float* q_a_w   = (const float*)d_in[1];
  const float* q_a_ln  = (const float*)d_in[2];
  const float* q_b_w   = (const float*)d_in[3];
  const float* kv_a_w  = (const float*)d_in[4];
  const float* kv_a_ln = (const float*)d_in[5];
  const float* kv_b_w  = (const float*)d_in[6];
  const float* o_w     = (const float*)d_in[7];

  char* ws = (char*)d_ws;
  size_t off = 0;
  auto alloc = [&](size_t bytes){ void* p = ws + off; off += bytes; return p; };
  u16*  Wqa   = (u16*)alloc(1536ull*2048*2);      // adjacent: merged [2560][2048]
  u16*  Wkva  = (u16*)alloc(1024ull*2048*2);
  u16*  Wqb   = (u16*)alloc(3072ull*1536*2);
  u16*  Wkvb  = (u16*)alloc(2048ull*512*2);
  u16*  Wo    = (u16*)alloc(2048ull*2048*2);
  u16*  XB    = (u16*)alloc(4096ull*2048*2);      // x bf16 -> later attn output
  u16*  R23   = (u16*)alloc(4096ull*2560*2);      // merged latents bf16 -> later KVB
  u16*  QB    = (u16*)alloc(4096ull*3072*2);
  u16*  Qlat  = (u16*)alloc(4096ull*1536*2);
  u16*  KVlat = (u16*)alloc(4096ull*512*2);
  u16*  Kf    = (u16*)alloc(2ull*8*2048*192*2);
  u16*  Vt    = (u16*)alloc(2ull*8*128*2048*2);
  float* cosT = (float*)alloc(2048ull*32*4);
  float* sinT = (float*)alloc(2048ull*32*4);
  (void)ws_size; (void)in_sizes; (void)n_in; (void)out_size;

  u16* KVB = R23;                                 // R23 dead after norm_split

  prep_kernel<<<23296, 256, 0, stream>>>(hs, XB, q_a_w, Wqa, kv_a_w, Wkva,
                                         q_b_w, Wqb, kv_b_w, Wkvb, o_w, Wo, cosT, sinT);
  // merged q_a + kv_a: N = 2560, bf16 out
  gemm_bt<1><<<dim3(20, 32), 256, 0, stream>>>(XB, Wqa, R23, 4096, 2560, 2048, 1.0f);
  norm_split<<<4096, 256, 0, stream>>>(R23, q_a_ln, kv_a_ln, cosT, sinT, Qlat, KVlat, Kf);
  gemm_qb_kvb<<<1280, 256, 0, stream>>>(Qlat, Wqb, QB, cosT, sinT, KVlat, Wkvb, KVB);
  kv_rearrange<<<512, 256, 0, stream>>>(KVB, Vt, Kf);
  attn_kernel<<<512, 256, 0, stream>>>(QB, Kf, Vt, XB);
  gemm_bt<0><<<dim3(16, 32), 256, 0, stream>>>(XB, Wo, (float*)d_out, 4096, 2048, 2048, 1.0f);
}

// Round 16
// 344.078 us; speedup vs baseline: 1.0114x; 1.0114x over previous
//
#include <hip/hip_runtime.h>

using u16 = unsigned short;
using u32 = unsigned int;

typedef float f32x4 __attribute__((ext_vector_type(4)));
typedef __bf16 bf16x8 __attribute__((ext_vector_type(8)));

// ---------- helpers ----------
__device__ __forceinline__ u16 f2bf(float f){
  u32 u = __builtin_bit_cast(u32, f);
  u32 r = (u + 0x7fffu + ((u >> 16) & 1u)) >> 16;   // RNE
  return (u16)r;
}
__device__ __forceinline__ float bf2f(u16 h){
  u32 u = ((u32)h) << 16;
  return __builtin_bit_cast(float, u);
}
__device__ __forceinline__ void gl2lds16(const void* g, void* l){
  __builtin_amdgcn_global_load_lds((const __attribute__((address_space(1))) u32*)g,
                                   (__attribute__((address_space(3))) u32*)l, 16, 0, 0);
}
__device__ __forceinline__ int swz24(int ck, int r){ return (ck & 24) | ((ck ^ r) & 7); }
__device__ __forceinline__ u32 cvtpk_bf16(float a, float b){
  u32 r; asm("v_cvt_pk_bf16_f32 %0, %1, %2" : "=v"(r) : "v"(a), "v"(b)); return r;
}
__device__ __forceinline__ float exp2_raw(float x){
  float r; asm("v_exp_f32 %0, %1" : "=v"(r) : "v"(x)); return r;   // 2^x
}

// ---------- prep: 5 weight transposes + rope tables + x cvt, one launch ----------
__global__ __launch_bounds__(256) void prep_kernel(const float* __restrict__ hs, u16* __restrict__ XB,
                                                   const float* __restrict__ q_a_w,  u16* __restrict__ Wqa,
                                                   const float* __restrict__ kv_a_w, u16* __restrict__ Wkva,
                                                   const float* __restrict__ q_b_w,  u16* __restrict__ Wqb,
                                                   const float* __restrict__ kv_b_w, u16* __restrict__ Wkvb,
                                                   const float* __restrict__ o_w,    u16* __restrict__ Wo,
                                                   float* __restrict__ cosT, float* __restrict__ sinT){
  __shared__ float tile[32][33];
  const int id = blockIdx.x;
  if (id >= 15104){                    // cvt x -> bf16
    long i = ((long)(id - 15104)*256 + threadIdx.x)*4;
    float4 v = *(const float4*)(hs + i);
    u16 o[4] = { f2bf(v.x), f2bf(v.y), f2bf(v.z), f2bf(v.w) };
    *(ushort4*)(XB + i) = *(ushort4*)o;
    return;
  }
  if (id >= 14848){                    // rope tables (f64 trig)
    int idx = (id - 14848)*256 + threadIdx.x;
    int t = idx >> 5, d = idx & 31;
    double inv = pow(10000.0, -(double)d / 32.0);
    double a = (double)t * inv;
    cosT[idx] = (float)cos(a);
    sinT[idx] = (float)sin(a);
    return;
  }
  const float* in; u16* out; int K, N, lid;
  if      (id <  3072){ in = q_a_w;  out = Wqa;  K = 2048; N = 1536; lid = id; }
  else if (id <  5120){ in = kv_a_w; out = Wkva; K = 2048; N = 1024; lid = id - 3072; }
  else if (id <  9728){ in = q_b_w;  out = Wqb;  K = 1536; N = 3072; lid = id - 5120; }
  else if (id < 10752){ in = kv_b_w; out = Wkvb; K =  512; N = 2048; lid = id - 9728; }
  else                { in = o_w;    out = Wo;   K = 2048; N = 2048; lid = id - 10752; }
  const int tx = threadIdx.x & 31, ty = threadIdx.x >> 5;
  const int nb = N >> 5;
  const int n0 = (lid % nb)*32, k0 = (lid / nb)*32;
  for (int i = ty; i < 32; i += 8)
    tile[i][tx] = in[(size_t)(k0+i)*N + n0+tx];
  __syncthreads();
  for (int i = ty; i < 32; i += 8)
    out[(size_t)(n0+i)*K + k0+tx] = f2bf(tile[tx][i]);
}

// ---------- block remap: XCD-grouped, 4 M-panels share each B-panel per XCD ----------
__device__ __forceinline__ void remap_id(int id, int& bx, int& by){
  bx = id >> 5;
  by = ((id & 7) << 2) | ((id >> 3) & 3);
}

// ---------- m97-style 128x128 bf16 MFMA GEMM (single-buffer, proven) ----------
template<int OUT_BF16>
__global__ __launch_bounds__(256) void gemm_bt(const u16* __restrict__ A,
                                               const u16* __restrict__ Bt,
                                               void* __restrict__ Cout,
                                               int M, int N, int K, float cscale){
  __shared__ u16 As[128*32];
  __shared__ u16 Bs[128*32];
  const int tid = threadIdx.x, lane = tid & 63, wave = tid >> 6;
  int bx, by; remap_id(blockIdx.y*gridDim.x + blockIdx.x, bx, by);
  const int m0 = by*128, n0 = bx*128;
  const int wm = (wave >> 1)*64, wn = (wave & 1)*64;
  const int g = lane >> 4, lr = lane & 15;
  f32x4 acc[4][4] = {};
  const int sr = (wave*2)*16 + (lane >> 2);
  const int sc = (lane & 3)*8;
  for (int k0 = 0; k0 < K; k0 += 32){
    __syncthreads();
    #pragma unroll
    for (int i = 0; i < 2; i++){
      int c = wave*2 + i;
      int r = sr + i*16;
      gl2lds16(A  + (size_t)(m0+r)*K + k0 + sc, (char*)As + c*1024);
      gl2lds16(Bt + (size_t)(n0+r)*K + k0 + sc, (char*)Bs + c*1024);
    }
    __syncthreads();
    bf16x8 af[4], bfr[4];
    #pragma unroll
    for (int mi = 0; mi < 4; mi++) af[mi]  = *reinterpret_cast<const bf16x8*>(&As[(wm+mi*16+lr)*32 + g*8]);
    #pragma unroll
    for (int ni = 0; ni < 4; ni++) bfr[ni] = *reinterpret_cast<const bf16x8*>(&Bs[(wn+ni*16+lr)*32 + g*8]);
    #pragma unroll
    for (int mi = 0; mi < 4; mi++)
      #pragma unroll
      for (int ni = 0; ni < 4; ni++)
        acc[mi][ni] = __builtin_amdgcn_mfma_f32_16x16x32_bf16(af[mi], bfr[ni], acc[mi][ni], 0,0,0);
  }
  #pragma unroll
  for (int mi = 0; mi < 4; mi++)
    #pragma unroll
    for (int ni = 0; ni < 4; ni++)
      #pragma unroll
      for (int r = 0; r < 4; r++){
        int row = m0 + wm + mi*16 + g*4 + r;
        int col = n0 + wn + ni*16 + lr;
        float v = acc[mi][ni][r];
        if (OUT_BF16) ((u16*)Cout)[(size_t)row*N + col] = f2bf(v*cscale);
        else          ((float*)Cout)[(size_t)row*N + col] = v;
      }
}

// ---------- merged q_b (+RoPE, qscale*log2e) and kv_b GEMM in one launch ----------
__global__ __launch_bounds__(256) void gemm_qb_kvb(const u16* __restrict__ Qlat,
                                                   const u16* __restrict__ Wqb,
                                                   u16* __restrict__ QB,
                                                   const float* __restrict__ cosT,
                                                   const float* __restrict__ sinT,
                                                   const u16* __restrict__ KVlat,
                                                   const u16* __restrict__ Wkvb,
                                                   u16* __restrict__ KVB){
  constexpr float qscale = 0.07216878364870322f * 1.44269504088896340f;  // 192^-0.5 * log2(e)
  __shared__ u16 As[128*32];
  __shared__ u16 Bs[128*32];
  const int id = blockIdx.x;
  const u16 *A, *Bt; u16* C; int N, K; bool isqb;
  int bx, by;
  if (id < 768){ A = Qlat;  Bt = Wqb;  C = QB;  N = 3072; K = 1536; isqb = true;  remap_id(id, bx, by); }
  else         { A = KVlat; Bt = Wkvb; C = KVB; N = 2048; K =  512; isqb = false; remap_id(id - 768, bx, by); }
  const int tid = threadIdx.x, lane = tid & 63, wave = tid >> 6;
  const int m0 = by*128, n0 = bx*128;
  const int wm = (wave >> 1)*64, wn = (wave & 1)*64;
  const int g = lane >> 4, lr = lane & 15;
  f32x4 acc[4][4] = {};
  const int sr = (wave*2)*16 + (lane >> 2);
  const int sc = (lane & 3)*8;
  for (int k0 = 0; k0 < K; k0 += 32){
    __syncthreads();
    #pragma unroll
    for (int i = 0; i < 2; i++){
      int c = wave*2 + i;
      int r = sr + i*16;
      gl2lds16(A  + (size_t)(m0+r)*K + k0 + sc, (char*)As + c*1024);
      gl2lds16(Bt + (size_t)(n0+r)*K + k0 + sc, (char*)Bs + c*1024);
    }
    __syncthreads();
    bf16x8 af[4], bfr[4];
    #pragma unroll
    for (int mi = 0; mi < 4; mi++) af[mi]  = *reinterpret_cast<const bf16x8*>(&As[(wm+mi*16+lr)*32 + g*8]);
    #pragma unroll
    for (int ni = 0; ni < 4; ni++) bfr[ni] = *reinterpret_cast<const bf16x8*>(&Bs[(wn+ni*16+lr)*32 + g*8]);
    #pragma unroll
    for (int mi = 0; mi < 4; mi++)
      #pragma unroll
      for (int ni = 0; ni < 4; ni++)
        acc[mi][ni] = __builtin_amdgcn_mfma_f32_16x16x32_bf16(af[mi], bfr[ni], acc[mi][ni], 0,0,0);
  }
  if (isqb){
    const bool rope = (((n0 + wn) >> 6) % 3) == 2;
    #pragma unroll
    for (int mi = 0; mi < 4; mi++)
      #pragma unroll
      for (int r = 0; r < 4; r++){
        int row = m0 + wm + mi*16 + g*4 + r;
        int t = row & 2047;
        u16* crow = C + (size_t)row*3072 + n0 + wn;
        if (rope){
          #pragma unroll
          for (int np = 0; np < 2; np++){
            int dp = np*16 + lr;
            float x1 = acc[mi][np][r]*qscale, x2 = acc[mi][np+2][r]*qscale;
            float cv = cosT[t*32 + dp], sv = sinT[t*32 + dp];
            crow[dp]      = f2bf(x1*cv - x2*sv);
            crow[dp + 32] = f2bf(x2*cv + x1*sv);
          }
        } else {
          #pragma unroll
          for (int ni = 0; ni < 4; ni++)
            crow[ni*16 + lr] = f2bf(acc[mi][ni][r]*qscale);
        }
      }
  } else {
    #pragma unroll
    for (int mi = 0; mi < 4; mi++)
      #pragma unroll
      for (int ni = 0; ni < 4; ni++)
        #pragma unroll
        for (int r = 0; r < 4; r++){
          int row = m0 + wm + mi*16 + g*4 + r;
          int col = n0 + wn + ni*16 + lr;
          C[(size_t)row*2048 + col] = f2bf(acc[mi][ni][r]);
        }
  }
}

// ---------- merged rmsnorm(q) + rmsnorm(kv)+rope(k) over R23 rows ----------
__global__ __launch_bounds__(256) void norm_split(const u16* __restrict__ R23,
                                                  const float* __restrict__ q_ln,
                                                  const float* __restrict__ kv_ln,
                                                  const float* __restrict__ cosT,
                                                  const float* __restrict__ sinT,
                                                  u16* __restrict__ Qlat,
                                                  u16* __restrict__ KVlat,
                                                  u16* __restrict__ Kf){
  int row = blockIdx.x;                       // 0..4095
  int t = row & 2047, b = row >> 11;
  const u16* x = R23 + (size_t)row*2560;
  int c = threadIdx.x;
  float xq[8]; float ssq = 0.f;
  if (c < 192){
    ushort4 a = *(const ushort4*)(x + c*8);
    ushort4 bq = *(const ushort4*)(x + c*8 + 4);
    u16 e[8] = {a.x,a.y,a.z,a.w,bq.x,bq.y,bq.z,bq.w};
    #pragma unroll
    for (int j = 0; j < 8; j++){ xq[j] = bf2f(e[j]); ssq += xq[j]*xq[j]; }
  }
  float xk[4]; float ssk = 0.f;
  if (c < 128){
    ushort4 a = *(const ushort4*)(x + 1536 + c*4);
    u16 e[4] = {a.x,a.y,a.z,a.w};
    #pragma unroll
    for (int j = 0; j < 4; j++){ xk[j] = bf2f(e[j]); ssk += xk[j]*xk[j]; }
  }
  #pragma unroll
  for (int m = 1; m < 64; m <<= 1){
    ssq += __shfl_xor(ssq, m, 64);
    ssk += __shfl_xor(ssk, m, 64);
  }
  __shared__ float pq[4], pk[4];
  if ((c & 63) == 0){ pq[c >> 6] = ssq; pk[c >> 6] = ssk; }
  __syncthreads();
  float invq = rsqrtf((pq[0]+pq[1]+pq[2]+pq[3]) / 1536.0f + 1e-6f);
  float invk = rsqrtf((pk[0]+pk[1]+pk[2]+pk[3]) / 512.0f + 1e-6f);
  if (c < 192){
    u16 o[8];
    #pragma unroll
    for (int j = 0; j < 8; j++) o[j] = f2bf(xq[j]*invq*q_ln[c*8+j]);
    *(ushort4*)(Qlat + (size_t)row*1536 + c*8)     = *(ushort4*)o;
    *(ushort4*)(Qlat + (size_t)row*1536 + c*8 + 4) = *(ushort4*)(o+4);
  }
  if (c < 128){
    u16 o[4];
    #pragma unroll
    for (int j = 0; j < 4; j++) o[j] = f2bf(xk[j]*invk*kv_ln[c*4+j]);
    *(ushort4*)(KVlat + (size_t)row*512 + c*4) = *(ushort4*)o;
  }
  int kh = c >> 5, dp = c & 31;
  float x1 = bf2f(x[2048 + kh*64 + dp]), x2 = bf2f(x[2048 + kh*64 + dp + 32]);
  float cv = cosT[t*32 + dp], sv = sinT[t*32 + dp];
  float o1 = x1*cv - x2*sv;
  float o2 = x2*cv + x1*sv;
  u16* kr = Kf + ((size_t)(b*8 + kh)*2048 + t)*192;
  int c1 = 128 + dp, c2 = 128 + dp + 32;
  kr[(swz24(c1 >> 3, t) << 3) | (c1 & 7)] = f2bf(o1);
  kr[(swz24(c2 >> 3, t) << 3) | (c2 & 7)] = f2bf(o2);
}

// ---------- kv rearrange: knope copy -> Kf (swizzled) + V transpose -> vT ----------
__global__ __launch_bounds__(256) void kv_rearrange(const u16* __restrict__ kv,
                                                    u16* __restrict__ vT,
                                                    u16* __restrict__ Kf){
  int bid = blockIdx.x;                        // 2*8*32
  int tt = bid & 31, kvh = (bid >> 5) & 7, b = bid >> 8;
  int t0 = tt*64;
  __shared__ u16 tile[64][136];
  int tid = threadIdx.x;
  #pragma unroll
  for (int i = 0; i < 4; i++){
    int c2 = tid + i*256;
    int rr = c2 >> 4, ck = c2 & 15;
    int t = t0 + rr;
    int ck2 = (ck & 8) | ((ck ^ t) & 7);
    uint4 v = *(const uint4*)(kv + ((size_t)(b*2048 + t))*2048 + kvh*256 + ck*8);
    *(uint4*)(Kf + ((size_t)(b*8 + kvh)*2048 + t)*192 + ck2*8) = v;
  }
  #pragma unroll
  for (int i = 0; i < 4; i++){
    int c = tid + i*256;
    int r = c >> 4, ck = c & 15;
    const u16* src = kv + ((size_t)(b*2048 + t0 + r))*2048 + kvh*256 + 128 + ck*8;
    *(uint4*)&tile[r][ck*8] = *(const uint4*)src;
  }
  __syncthreads();
  #pragma unroll
  for (int i = 0; i < 4; i++){
    int c = tid + i*256;
    int vd = c >> 3, tc = c & 7;
    int stc = tc ^ (vd & 7);
    uint4 tv;
    u16* tp = (u16*)&tv;
    #pragma unroll
    for (int j = 0; j < 8; j++) tp[j] = tile[tc*8 + j][vd];
    *(uint4*)(vT + ((size_t)(b*8 + kvh)*128 + vd)*2048 + t0 + stc*8) = tv;
  }
}

// ---------- flash attention: champion + UNPINNED softmax/PV overlap ----------
// Q PRE-SCALED by 192^-0.5 * log2(e): softmax uses raw v_exp_f32 (2^x).
// NOTE: no fence between P-stores and ap-loads — DS ops are in-order per wave,
// Ps is wave-private, and may-alias analysis preserves store->load program order.
// This lets the scheduler interleave PV MFMAs with the other q-group's softmax VALU.
__global__ __launch_bounds__(256, 2) void attn_kernel(const u16* __restrict__ Q,
                                                      const u16* __restrict__ Kf,
                                                      const u16* __restrict__ Vt,
                                                      u16* __restrict__ Oa){
  constexpr int T = 2048;
  constexpr int NT = T/64;
  __shared__ u16 Ks[64*192];
  __shared__ u16 Vs[2][128*64];
  __shared__ u16 Ps[4][2048];
  const int tid = threadIdx.x, lane = tid & 63, wave = tid >> 6;
  const int g = lane >> 4, lr = lane & 15;

  const int wg = blockIdx.x;                 // 0..511
  const int role = (wg & 7)*64 + (wg >> 3);
  const int grp = role >> 5;                 // b*8 + kvh
  const int b = grp >> 3, kvh = grp & 7;
  const int within = role & 31;
  const int h = kvh*2 + (within >> 4);
  const int q0 = (within & 15)*128 + wave*32;

  bf16x8 aq[2][6];
  #pragma unroll
  for (int qg = 0; qg < 2; qg++){
    const u16* qrow = Q + ((size_t)b*T + q0 + qg*16 + lr)*3072 + h*192;
    #pragma unroll
    for (int kc = 0; kc < 6; kc++)
      aq[qg][kc] = *reinterpret_cast<const bf16x8*>(qrow + kc*32 + g*8);
  }
  const u16* Kbase = Kf + (size_t)(b*8 + kvh)*T*192;
  const u16* Vbase = Vt + (size_t)(b*8 + kvh)*128*T;

  f32x4 ovb[2][8] = {};
  float mq[2] = {-1e30f, -1e30f};
  float lq[2] = {0.f, 0.f};

  auto stageK = [&](int kt){
    const u16* ksrc = Kbase + (size_t)kt*12288 + wave*3072 + lane*8;
    #pragma unroll
    for (int i = 0; i < 6; i++)
      gl2lds16(ksrc + i*512, (char*)Ks + (wave*6 + i)*1024);
  };
  auto stageV = [&](int kt, int buf){
    #pragma unroll
    for (int i = 0; i < 4; i++){
      int c = wave*4 + i;
      const u16* vsrc = Vbase + (size_t)(c*8 + (lane >> 3))*T + kt*64 + (lane & 7)*8;
      gl2lds16(vsrc, (char*)(&Vs[0][0]) + buf*16384 + c*1024);
    }
  };

  stageK(0);
  stageV(0, 0);
  __syncthreads();

  int buf = 0;
  for (int kt = 0; kt < NT; kt++){
    const bool notlast = (kt + 1 < NT);
    if (notlast) stageV(kt + 1, buf ^ 1);

    // ---- QK^T swapped: lane (g,lr) reg r = S[kv=nb*16+g*4+r][q=lr] ----
    f32x4 s[2][4];
    __builtin_amdgcn_s_setprio(1);
    #pragma unroll
    for (int nb = 0; nb < 4; nb++){
      const int row = nb*16 + lr;
      f32x4 a0 = {0.f,0.f,0.f,0.f}, a1 = {0.f,0.f,0.f,0.f};
      #pragma unroll
      for (int kc = 0; kc < 6; kc++){
        int ckl = swz24(kc*4 + g, row);
        bf16x8 kf = *reinterpret_cast<const bf16x8*>(&Ks[row*192 + ckl*8]);
        a0 = __builtin_amdgcn_mfma_f32_16x16x32_bf16(kf, aq[0][kc], a0, 0,0,0);
        a1 = __builtin_amdgcn_mfma_f32_16x16x32_bf16(kf, aq[1][kc], a1, 0,0,0);
      }
      s[0][nb] = a0; s[1][nb] = a1;
    }
    __builtin_amdgcn_s_setprio(0);

    // barrier_A: Ks reads done wave-wide. lgkm-only (V prefetch stays in flight).
    asm volatile("s_waitcnt lgkmcnt(0)" ::: "memory");
    __builtin_amdgcn_s_barrier();
    __builtin_amdgcn_sched_barrier(0);   // pin stageK AFTER the barrier
    if (notlast) stageK(kt + 1);

    // ---- in-register softmax (log2 domain, raw v_exp); P -> Ps ----
    #pragma unroll
    for (int qg = 0; qg < 2; qg++){
      float pm = s[qg][0][0];
      #pragma unroll
      for (int nb = 0; nb < 4; nb++)
        #pragma unroll
        for (int r = 0; r < 4; r++)
          if (nb || r) pm = fmaxf(pm, s[qg][nb][r]);
      pm = fmaxf(pm, __shfl_xor(pm, 16, 64));
      pm = fmaxf(pm, __shfl_xor(pm, 32, 64));
      if (!__all(pm <= mq[qg] + 8.f)){
        float mn = fmaxf(mq[qg], pm);
        float corr = exp2_raw(mq[qg] - mn);
        mq[qg] = mn;
        lq[qg] *= corr;
        #pragma unroll
        for (int r = 0; r < 4; r++){
          float cr = __shfl(corr, (lane & 48) | (g*4 + r), 64);
          #pragma unroll
          for (int vb = 0; vb < 8; vb++) ovb[qg][vb][r] *= cr;
        }
      }
      float ls = 0.f;
      #pragma unroll
      for (int nb = 0; nb < 4; nb++){
        float e0 = exp2_raw(s[qg][nb][0] - mq[qg]);
        float e1 = exp2_raw(s[qg][nb][1] - mq[qg]);
        float e2 = exp2_raw(s[qg][nb][2] - mq[qg]);
        float e3 = exp2_raw(s[qg][nb][3] - mq[qg]);
        ls += (e0 + e1) + (e2 + e3);
        int stc = (2*nb + (g >> 1)) ^ (lr & 7);
        volatile u32* p = (volatile u32*)&Ps[wave][qg*1024 + lr*64 + stc*8 + (g & 1)*4];
        p[0] = cvtpk_bf16(e0, e1);
        p[1] = cvtpk_bf16(e2, e3);
      }
      lq[qg] += ls;
    }

    // (no fence / sched_barrier here: DS in-order per wave; scheduler may overlap)

    // ---- PV: A = P from Ps b128, B = V from Vs[buf] b128 ----
    bf16x8 ap[2][2];
    #pragma unroll
    for (int qg = 0; qg < 2; qg++)
      #pragma unroll
      for (int k2 = 0; k2 < 2; k2++){
        int ck = (k2*4 + g) ^ (lr & 7);
        ap[qg][k2] = *reinterpret_cast<const bf16x8*>(&Ps[wave][qg*1024 + lr*64 + ck*8]);
      }
    __builtin_amdgcn_s_setprio(1);
    #pragma unroll
    for (int vb = 0; vb < 8; vb++)
      #pragma unroll
      for (int k2 = 0; k2 < 2; k2++){
        int vd = vb*16 + lr;
        int ck = (k2*4 + g) ^ (vd & 7);
        bf16x8 bv = *reinterpret_cast<const bf16x8*>(&Vs[buf][vd*64 + ck*8]);
        ovb[0][vb] = __builtin_amdgcn_mfma_f32_16x16x32_bf16(ap[0][k2], bv, ovb[0][vb], 0,0,0);
        ovb[1][vb] = __builtin_amdgcn_mfma_f32_16x16x32_bf16(ap[1][k2], bv, ovb[1][vb], 0,0,0);
      }
    __builtin_amdgcn_s_setprio(0);

    if (notlast) __syncthreads();
    buf ^= 1;
  }

  #pragma unroll
  for (int qg = 0; qg < 2; qg++){
    float lt = lq[qg];
    lt += __shfl_xor(lt, 16, 64);
    lt += __shfl_xor(lt, 32, 64);
    float invq = 1.0f / lt;
    float inv_r[4];
    #pragma unroll
    for (int r = 0; r < 4; r++)
      inv_r[r] = __shfl(invq, (lane & 48) | (g*4 + r), 64);
    u16* obase = Oa + ((size_t)b*T + q0 + qg*16)*2048 + h*128;
    #pragma unroll
    for (int vb = 0; vb < 8; vb++)
      #pragma unroll
      for (int r = 0; r < 4; r++)
        obase[(size_t)(g*4 + r)*2048 + vb*16 + lr] = f2bf(ovb[qg][vb][r]*inv_r[r]);
  }
}

// ---------- launch ----------
extern "C" void kernel_launch(void* const* d_in, const int* in_sizes, int n_in,
                              void* d_out, int out_size, void* d_ws, size_t ws_size,
                              hipStream_t stream){
  const float* hs      = (const float*)d_in[0];
  const float* q_a_w   = (const float*)d_in[1];
  const float* q_a_ln  = (const float*)d_in[2];
  const float* q_b_w   = (const float*)d_in[3];
  const float* kv_a_w  = (const float*)d_in[4];
  const float* kv_a_ln = (const float*)d_in[5];
  const float* kv_b_w  = (const float*)d_in[6];
  const float* o_w     = (const float*)d_in[7];

  char* ws = (char*)d_ws;
  size_t off = 0;
  auto alloc = [&](size_t bytes){ void* p = ws + off; off += bytes; return p; };
  u16*  Wqa   = (u16*)alloc(1536ull*2048*2);      // adjacent: merged [2560][2048]
  u16*  Wkva  = (u16*)alloc(1024ull*2048*2);
  u16*  Wqb   = (u16*)alloc(3072ull*1536*2);
  u16*  Wkvb  = (u16*)alloc(2048ull*512*2);
  u16*  Wo    = (u16*)alloc(2048ull*2048*2);
  u16*  XB    = (u16*)alloc(4096ull*2048*2);      // x bf16 -> later attn output
  u16*  R23   = (u16*)alloc(4096ull*2560*2);      // merged latents bf16 -> later KVB
  u16*  QB    = (u16*)alloc(4096ull*3072*2);
  u16*  Qlat  = (u16*)alloc(4096ull*1536*2);
  u16*  KVlat = (u16*)alloc(4096ull*512*2);
  u16*  Kf    = (u16*)alloc(2ull*8*2048*192*2);
  u16*  Vt    = (u16*)alloc(2ull*8*128*2048*2);
  float* cosT = (float*)alloc(2048ull*32*4);
  float* sinT = (float*)alloc(2048ull*32*4);
  (void)ws_size; (void)in_sizes; (void)n_in; (void)out_size;

  u16* KVB = R23;                                 // R23 dead after norm_split

  prep_kernel<<<23296, 256, 0, stream>>>(hs, XB, q_a_w, Wqa, kv_a_w, Wkva,
                                         q_b_w, Wqb, kv_b_w, Wkvb, o_w, Wo, cosT, sinT);
  gemm_bt<1><<<dim3(20, 32), 256, 0, stream>>>(XB, Wqa, R23, 4096, 2560, 2048, 1.0f);
  norm_split<<<4096, 256, 0, stream>>>(R23, q_a_ln, kv_a_ln, cosT, sinT, Qlat, KVlat, Kf);
  gemm_qb_kvb<<<1280, 256, 0, stream>>>(Qlat, Wqb, QB, cosT, sinT, KVlat, Wkvb, KVB);
  kv_rearrange<<<512, 256, 0, stream>>>(KVB, Vt, Kf);
  attn_kernel<<<512, 256, 0, stream>>>(QB, Kf, Vt, XB);
  gemm_bt<0><<<dim3(16, 32), 256, 0, stream>>>(XB, Wo, (float*)d_out, 4096, 2048, 2048, 1.0f);
}